// Round 4
// baseline (698.643 us; speedup 1.0000x reference)
//
#include <hip/hip_runtime.h>

#define NN 100000
#define NE 1600000
#define HD 128
#define NG 128
#define NC 10
#define EPSV 1e-5f

#define BSH 9                      // 512 dst nodes per bucket
#define NBKT ((NN + 511) >> 9)     // 196
#define BIN_BLOCKS ((NE + 4095) / 4096)  // 391

typedef __attribute__((ext_vector_type(8))) short short8;
typedef __attribute__((ext_vector_type(4))) float f32x4;

__device__ __forceinline__ float b2f(ushort u){ return __uint_as_float(((unsigned)u)<<16); }
__device__ __forceinline__ ushort f2b(float f){
  unsigned u = __float_as_uint(f);
  unsigned r = (u + 0x7FFFu + ((u>>16)&1u)) >> 16;   // RNE
  return (ushort)r;
}

// ---------------- init: granges + weight-prep + zeroing (replaces 3 memsets + 2 kernels) ----
__global__ __launch_bounds__(256)
void k_init(const int* __restrict__ batch, int* __restrict__ gstart,
            const float* __restrict__ w1, const float* __restrict__ w2,
            const float* __restrict__ w3, ushort* __restrict__ wT,
            int* __restrict__ gbhist, float* __restrict__ s12_base)
{
  int b = blockIdx.x, t = threadIdx.x;
  if(b < 391){                       // granges: batch sorted -> contiguous segments
    int n = b*256 + t;
    if(n >= NN) return;
    int bb = batch[n];
    if(n == 0){
      for(int g=0; g<=bb; g++) gstart[g] = 0;
      int last = batch[NN-1];
      for(int g=last+1; g<=NG; g++) gstart[g] = NN;
    } else {
      int bp = batch[n-1];
      for(int g=bp+1; g<=bb; g++) gstart[g] = n;
    }
  } else if(b < 394){                // wT[layer][h][k] = bf16(w[k][h])
    const float* w = (b == 391) ? w1 : (b == 392) ? w2 : w3;
    ushort* o = wT + (b-391)*16384;
    #pragma unroll 4
    for(int i=0;i<64;i++){
      int e = i*256 + t;
      int k = e>>7, h = e&127;
      o[h*128 + k] = f2b(w[e]);
    }
  } else if(b < 398){                // zero S1+S2 (contiguous 32768 floats)
    #pragma unroll 8
    for(int i=0;i<32;i++) s12_base[(b-394)*8192 + i*256 + t] = 0.f;
  } else {                           // zero gbhist
    if(t < NBKT) gbhist[t] = 0;
  }
}

// ---------------- pass 0: global bucket histogram ----------------
__global__ __launch_bounds__(256) void k_bhist(const int* __restrict__ ei, int* __restrict__ gbhist){
  __shared__ int h[NBKT];
  int t = threadIdx.x;
  if(t < NBKT) h[t] = 0;
  __syncthreads();
  int base = blockIdx.x*4096;
  #pragma unroll
  for(int i=0;i<16;i++){
    int e = base + i*256 + t;
    if(e < NE) atomicAdd(&h[ei[NE + e] >> BSH], 1);
  }
  __syncthreads();
  if(t < NBKT && h[t]) atomicAdd(&gbhist[t], h[t]);
}

__global__ void k_bscan(const int* __restrict__ gbhist, int* __restrict__ bucket_base,
                        int* __restrict__ bucket_cursor, int* __restrict__ rowstart){
  __shared__ int lds[256];
  int t = threadIdx.x;
  int v = (t < NBKT) ? gbhist[t] : 0;
  lds[t] = v; __syncthreads();
  for(int off=1; off<256; off<<=1){
    int y = lds[t]; int z = (t>=off)?lds[t-off]:0;
    __syncthreads(); lds[t] = y+z; __syncthreads();
  }
  int excl = (t>0)?lds[t-1]:0;
  if(t < NBKT){ bucket_base[t] = excl; bucket_cursor[t] = excl; }
  if(t == 0){ bucket_base[NBKT] = NE; rowstart[NN] = NE; }
}

// ---------------- pass 1: bin edges by dst bucket (LDS-staged, contiguous writes) ----------
__global__ __launch_bounds__(256) void k_bin(const int* __restrict__ ei, int* __restrict__ bucket_cursor,
                                             unsigned long long* __restrict__ ebuf){
  __shared__ unsigned long long eb[4096];
  __shared__ int hist[NBKT], lstart[NBKT], lcur[NBKT], rbase[NBKT];
  __shared__ int scanbuf[256];
  int t = threadIdx.x;
  if(t < NBKT) hist[t] = 0;
  __syncthreads();
  int base = blockIdx.x*4096;
  int nv = NE - base; if(nv > 4096) nv = 4096;
  int se[16], de[16];
  #pragma unroll
  for(int i=0;i<16;i++){
    int e = base + i*256 + t;
    if(e < NE){ se[i] = ei[e]; de[i] = ei[NE + e]; atomicAdd(&hist[de[i] >> BSH], 1); }
  }
  __syncthreads();
  int v = (t < NBKT) ? hist[t] : 0;
  scanbuf[t] = v; __syncthreads();
  for(int off=1; off<256; off<<=1){
    int y = scanbuf[t]; int z = (t>=off)?scanbuf[t-off]:0;
    __syncthreads(); scanbuf[t] = y+z; __syncthreads();
  }
  if(t < NBKT){
    int excl = (t>0)?scanbuf[t-1]:0;
    lstart[t] = excl; lcur[t] = excl;
    if(hist[t]) rbase[t] = atomicAdd(&bucket_cursor[t], hist[t]);
  }
  __syncthreads();
  #pragma unroll
  for(int i=0;i<16;i++){
    int e = base + i*256 + t;
    if(e < NE){
      int b = de[i] >> BSH;
      int idx = atomicAdd(&lcur[b], 1);
      eb[idx] = ((unsigned long long)(unsigned)de[i] << 32) | (unsigned)se[i];
    }
  }
  __syncthreads();
  #pragma unroll
  for(int i=0;i<16;i++){
    int slot = i*256 + t;
    if(slot < nv){
      unsigned long long v8 = eb[slot];
      int b = (int)(v8 >> 32) >> BSH;
      ebuf[rbase[b] + (slot - lstart[b])] = v8;
    }
  }
}

// ---------------- pass 2: per-bucket counting sort + rowstart + dinv ----------------
__global__ __launch_bounds__(256) void k_sort(const unsigned long long* __restrict__ ebuf,
                                              const int* __restrict__ bucket_base,
                                              int* __restrict__ srcs, int* __restrict__ rowstart,
                                              float* __restrict__ dinv){
  __shared__ int hist[512], cur[512];
  __shared__ int scanbuf[256];
  int b = blockIdx.x, t = threadIdx.x;
  int e0 = bucket_base[b], e1 = bucket_base[b+1];
  hist[t] = 0; hist[t+256] = 0;
  __syncthreads();
  for(int i = e0 + t; i < e1; i += 256){
    int dl = (int)(ebuf[i] >> 32) - (b << BSH);
    atomicAdd(&hist[dl], 1);
  }
  __syncthreads();
  int s0 = hist[2*t], s1 = hist[2*t+1];
  scanbuf[t] = s0 + s1; __syncthreads();
  for(int off=1; off<256; off<<=1){
    int y = scanbuf[t]; int z = (t>=off)?scanbuf[t-off]:0;
    __syncthreads(); scanbuf[t] = y+z; __syncthreads();
  }
  int excl = (t>0)?scanbuf[t-1]:0;
  cur[2*t] = excl; cur[2*t+1] = excl + s0;
  int d0 = (b << BSH) + 2*t, d1 = d0 + 1;
  if(d0 < NN){ rowstart[d0] = e0 + excl;      dinv[d0] = rsqrtf((float)(s0 + 1)); }
  if(d1 < NN){ rowstart[d1] = e0 + excl + s0; dinv[d1] = rsqrtf((float)(s1 + 1)); }
  __syncthreads();
  for(int i = e0 + t; i < e1; i += 256){
    unsigned long long v8 = ebuf[i];
    int dl = (int)(v8 >> 32) - (b << BSH);
    int pos = e0 + atomicAdd(&cur[dl], 1);
    srcs[pos] = (int)(unsigned)v8;
  }
}

// ---------------- MFMA GEMM: g[node][h] = bf16( dinv[node] * (norm_relu(in[node]) @ w)[h] ) ----
// NORM=0: raw fp32 input (layer 1). NORM=1: bf16 input + fused GraphNorm+ReLU.
template<int NORM>
__global__ __launch_bounds__(256)
void k_gemm(const void* __restrict__ in_, const ushort* __restrict__ wT,
            ushort* __restrict__ g, const float* __restrict__ dinv,
            const int* __restrict__ batch,
            const float* __restrict__ gw, const float* __restrict__ gb,
            const float* __restrict__ am_tab, const float* __restrict__ rs_tab)
{
  __shared__ ushort lds_a[128*136];
  __shared__ float sdinv[128];
  const int t = threadIdx.x;
  const int row0 = blockIdx.x * 128;

  { // stage A tile -> bf16
    const int l = t & 31;          // 4-feat slot (f0 = 4*l)
    const int rr = t >> 5;         // 0..7
    if(t < 128){
      int node = row0 + t;
      sdinv[t] = (node < NN) ? dinv[node] : 0.f;
    }
    float4 gwv, gbv;
    if(NORM){ gwv = ((const float4*)gw)[l]; gbv = ((const float4*)gb)[l]; }
    #pragma unroll 4
    for(int rb = 0; rb < 16; rb++){
      int r = rb*8 + rr;
      int node = row0 + r;
      float4 v = make_float4(0.f,0.f,0.f,0.f);
      if(node < NN){
        if(NORM){
          ushort4 raw = ((const ushort4*)in_)[(size_t)node*32 + l];
          v = make_float4(b2f(raw.x), b2f(raw.y), b2f(raw.z), b2f(raw.w));
          int gg = batch[node];
          float4 am = ((const float4*)am_tab)[gg*32 + l];
          float4 rs = ((const float4*)rs_tab)[gg*32 + l];
          v.x = fmaxf(gwv.x*(v.x-am.x)*rs.x + gbv.x, 0.f);
          v.y = fmaxf(gwv.y*(v.y-am.y)*rs.y + gbv.y, 0.f);
          v.z = fmaxf(gwv.z*(v.z-am.z)*rs.z + gbv.z, 0.f);
          v.w = fmaxf(gwv.w*(v.w-am.w)*rs.w + gbv.w, 0.f);
        } else {
          v = ((const float4*)in_)[(size_t)node*32 + l];
        }
      }
      ushort4 b4;
      b4.x = f2b(v.x); b4.y = f2b(v.y); b4.z = f2b(v.z); b4.w = f2b(v.w);
      *(ushort4*)(lds_a + r*136 + l*4) = b4;
    }
  }
  __syncthreads();

  const int wv = t >> 6;          // wave 0..3 -> cols wv*32 .. wv*32+31
  const int l  = t & 63;
  const int lc = l & 15, lk = l >> 4;

  short8 bfrag[2][4];
  #pragma unroll
  for(int tt=0; tt<2; tt++){
    int col = wv*32 + tt*16 + lc;
    #pragma unroll
    for(int s=0; s<4; s++)
      bfrag[tt][s] = *(const short8*)(wT + col*128 + s*32 + lk*8);
  }

  f32x4 acc[8][2];
  #pragma unroll
  for(int m=0;m<8;m++){ acc[m][0] = (f32x4)0.f; acc[m][1] = (f32x4)0.f; }

  #pragma unroll
  for(int m=0; m<8; m++){
    const ushort* ap = lds_a + (m*16 + lc)*136 + lk*8;
    #pragma unroll
    for(int s=0; s<4; s++){
      short8 a = *(const short8*)(ap + s*32);
      acc[m][0] = __builtin_amdgcn_mfma_f32_16x16x32_bf16(a, bfrag[0][s], acc[m][0], 0, 0, 0);
      acc[m][1] = __builtin_amdgcn_mfma_f32_16x16x32_bf16(a, bfrag[1][s], acc[m][1], 0, 0, 0);
    }
  }

  #pragma unroll
  for(int m=0; m<8; m++){
    #pragma unroll
    for(int tt=0; tt<2; tt++){
      int colg = wv*32 + tt*16 + lc;
      #pragma unroll
      for(int r=0; r<4; r++){
        int row = m*16 + lk*4 + r;
        int node = row0 + row;
        if(node < NN)
          g[(size_t)node*128 + colg] = f2b(acc[m][tt][r] * sdinv[row]);
      }
    }
  }
}

// ---------------- fused aggregation + GraphNorm stats ----------------
// out[n] = bf16( dinv[n]*(sum_{e->n} g[src] + g[n]) + bias ); S1/S2 += per-graph moments (fp32)
__global__ __launch_bounds__(256)
void k_agg(const ushort* __restrict__ g, const int* __restrict__ rowstart,
           const int* __restrict__ srcs, const float* __restrict__ dinv,
           const float* __restrict__ bias, const int* __restrict__ batch,
           ushort* __restrict__ outp, float* __restrict__ S1, float* __restrict__ S2)
{
  __shared__ float ls[256];        // [0..127]=S1 partial, [128..255]=S2 partial
  __shared__ int gmn, gmx;
  const int t = threadIdx.x;
  const int lane = t & 31;                 // 4-feat slot
  const int node = blockIdx.x*8 + (t >> 5);
  if(t == 0){ gmn = 0x7fffffff; gmx = -1; }
  ls[t] = 0.f;
  __syncthreads();

  const int e0 = rowstart[node], e1 = rowstart[node+1];
  float ax=0.f, ay=0.f, az=0.f, aw=0.f;
  float bx=0.f, by=0.f, bz=0.f, bw=0.f;
  const ushort4* gp = (const ushort4*)g;
  for(int e = e0; e < e1; e += 8){         // predicated 8-deep gather pipeline
    int si[8]; float m[8];
    #pragma unroll
    for(int i=0;i<8;i++){
      bool ok = (e+i) < e1;
      si[i] = ok ? srcs[e+i] : node;
      m[i] = ok ? 1.f : 0.f;
    }
    ushort4 v[8];
    #pragma unroll
    for(int i=0;i<8;i++) v[i] = gp[(size_t)si[i]*32 + lane];
    #pragma unroll
    for(int i=0;i<4;i++){
      ax = fmaf(m[i], b2f(v[i].x), ax); ay = fmaf(m[i], b2f(v[i].y), ay);
      az = fmaf(m[i], b2f(v[i].z), az); aw = fmaf(m[i], b2f(v[i].w), aw);
    }
    #pragma unroll
    for(int i=4;i<8;i++){
      bx = fmaf(m[i], b2f(v[i].x), bx); by = fmaf(m[i], b2f(v[i].y), by);
      bz = fmaf(m[i], b2f(v[i].z), bz); bw = fmaf(m[i], b2f(v[i].w), bw);
    }
  }
  ushort4 vs = gp[(size_t)node*32 + lane];
  float dv = dinv[node];
  float4 bv = ((const float4*)bias)[lane];
  float ox = dv*(ax+bx+b2f(vs.x))+bv.x;
  float oy = dv*(ay+by+b2f(vs.y))+bv.y;
  float oz = dv*(az+bz+b2f(vs.z))+bv.z;
  float ow = dv*(aw+bw+b2f(vs.w))+bv.w;

  ushort4 o4; o4.x = f2b(ox); o4.y = f2b(oy); o4.z = f2b(oz); o4.w = f2b(ow);
  ((ushort4*)outp)[(size_t)node*32 + lane] = o4;

  // --- fused GraphNorm stats (from pre-rounded fp32) ---
  int gg = batch[node];
  if(lane == 0){ atomicMin(&gmn, gg); atomicMax(&gmx, gg); }
  __syncthreads();
  if(gmn == gmx){                          // block entirely in one graph (common)
    atomicAdd(&ls[4*lane+0], ox); atomicAdd(&ls[4*lane+1], oy);
    atomicAdd(&ls[4*lane+2], oz); atomicAdd(&ls[4*lane+3], ow);
    atomicAdd(&ls[128+4*lane+0], ox*ox); atomicAdd(&ls[128+4*lane+1], oy*oy);
    atomicAdd(&ls[128+4*lane+2], oz*oz); atomicAdd(&ls[128+4*lane+3], ow*ow);
    __syncthreads();
    if(t < 128) atomicAdd(&S1[gmn*128 + t], ls[t]);
    else        atomicAdd(&S2[gmn*128 + (t-128)], ls[t]);
  } else {                                 // rare graph-boundary block
    atomicAdd(&S1[gg*128 + 4*lane+0], ox); atomicAdd(&S1[gg*128 + 4*lane+1], oy);
    atomicAdd(&S1[gg*128 + 4*lane+2], oz); atomicAdd(&S1[gg*128 + 4*lane+3], ow);
    atomicAdd(&S2[gg*128 + 4*lane+0], ox*ox); atomicAdd(&S2[gg*128 + 4*lane+1], oy*oy);
    atomicAdd(&S2[gg*128 + 4*lane+2], oz*oz); atomicAdd(&S2[gg*128 + 4*lane+3], ow*ow);
  }
}

// var = E[x^2] - (2a - a^2) m^2 ; tables: am = a*m, rs = rsqrt(var+eps). Self-zeroes S1/S2.
__global__ __launch_bounds__(256)
void k_finalize(float* __restrict__ S1, float* __restrict__ S2,
                const int* __restrict__ gstart, const float* __restrict__ ga,
                float* __restrict__ am_tab, float* __restrict__ rs_tab)
{
  int i = blockIdx.x*256 + threadIdx.x;
  if(i >= NG*HD) return;
  int g = i >> 7, f = i & 127;
  int len = gstart[g+1] - gstart[g];
  float cnt = (float)(len > 0 ? len : 1);
  float inv = 1.f/cnt;
  float m = S1[i]*inv, ex2 = S2[i]*inv;
  float a = ga[f];
  float var = ex2 - (2.f*a - a*a)*m*m;
  am_tab[i] = a*m;
  rs_tab[i] = rsqrtf(var + EPSV);
  S1[i] = 0.f; S2[i] = 0.f;       // ready for next layer
}

// ---------------- fused pool + head: one block per graph ----------------
__global__ __launch_bounds__(256)
void k_poolhead(const ushort* __restrict__ x, const int* __restrict__ gstart,
                const float* __restrict__ gw, const float* __restrict__ gb,
                const float* __restrict__ am_tab, const float* __restrict__ rs_tab,
                const float* __restrict__ lw, const float* __restrict__ lb,
                float* __restrict__ out)
{
  int g = blockIdx.x, t = threadIdx.x;
  int f = t & 127, sub = t >> 7;
  int s = gstart[g], e = gstart[g+1];
  float wv = gw[f], bv = gb[f];
  float am = am_tab[g*128+f], rs = rs_tab[g*128+f];
  float a1 = 0.f;
  for(int n = s + sub; n < e; n += 2){
    float v = b2f(x[(size_t)n*128 + f]);
    v = wv*(v-am)*rs + bv;
    a1 += fmaxf(v, 0.f);
  }
  __shared__ float sh[256];
  __shared__ float lg[NC];
  __shared__ float lse_s;
  sh[t] = a1;
  __syncthreads();
  if(t < 128){
    int len = e - s;
    float inv = 1.f/(float)(len > 0 ? len : 1);
    sh[t] = (sh[t] + sh[t+128]) * inv;
  }
  __syncthreads();
  if(t < NC){
    float acc = lb[t];
    for(int f2=0; f2<128; f2++) acc += sh[f2]*lw[f2*NC + t];
    lg[t] = acc;
  }
  __syncthreads();
  if(t == 0){
    float mx = -1e30f;
    for(int c=0;c<NC;c++) mx = fmaxf(mx, lg[c]);
    float sm = 0.f;
    for(int c=0;c<NC;c++) sm += expf(lg[c]-mx);
    lse_s = mx + logf(sm);
  }
  __syncthreads();
  if(t < NC) out[g*NC + t] = lg[t] - lse_s;
}

// ---------------- launch ----------------
extern "C" void kernel_launch(void* const* d_in, const int* in_sizes, int n_in,
                              void* d_out, int out_size, void* d_ws, size_t ws_size,
                              hipStream_t stream)
{
  const float* x    = (const float*)d_in[0];
  const int*   ei   = (const int*)d_in[1];
  const int*   batch= (const int*)d_in[2];
  const float* w1   = (const float*)d_in[3];
  const float* b1   = (const float*)d_in[4];
  const float* w2   = (const float*)d_in[5];
  const float* b2   = (const float*)d_in[6];
  const float* w3   = (const float*)d_in[7];
  const float* b3   = (const float*)d_in[8];
  const float* g1w  = (const float*)d_in[9];
  const float* g1b  = (const float*)d_in[10];
  const float* g1a  = (const float*)d_in[11];
  const float* g2w  = (const float*)d_in[12];
  const float* g2b  = (const float*)d_in[13];
  const float* g2a  = (const float*)d_in[14];
  const float* g3w  = (const float*)d_in[15];
  const float* g3b  = (const float*)d_in[16];
  const float* g3a  = (const float*)d_in[17];
  const float* lw   = (const float*)d_in[18];
  const float* lb   = (const float*)d_in[19];
  float* out = (float*)d_out;

  char* p = (char*)d_ws;
  auto take = [&](size_t nbytes){ char* q = p; p += (nbytes + 255) & ~(size_t)255; return q; };
  ushort* gbuf    = (ushort*)take((size_t)NN*HD*2);
  ushort* bufB    = (ushort*)take((size_t)NN*HD*2);
  ushort* wT      = (ushort*)take((size_t)3*HD*HD*2);
  unsigned long long* ebuf = (unsigned long long*)take((size_t)NE*8);
  int*   srcs     = (int*)  take((size_t)NE*4);
  int*   rowstart = (int*)  take((size_t)(NN+1)*4);
  float* dinv     = (float*)take((size_t)NN*4);
  int*   gbhist   = (int*)  take((size_t)NBKT*4);
  int*   bucket_base   = (int*)take((size_t)(NBKT+1)*4);
  int*   bucket_cursor = (int*)take((size_t)NBKT*4);
  int*   gstart   = (int*)  take((size_t)(NG+1)*4);
  float* S1       = (float*)take((size_t)NG*HD*4);   // contiguous with S2
  float* S2       = (float*)take((size_t)NG*HD*4);
  float* am_tab   = (float*)take((size_t)NG*HD*4);
  float* rs_tab   = (float*)take((size_t)NG*HD*4);
  if((size_t)(p - (char*)d_ws) > ws_size) return;  // workspace too small: fail visibly

  k_init  <<<399, 256, 0, stream>>>(batch, gstart, w1, w2, w3, wT, gbhist, S1);
  k_bhist <<<BIN_BLOCKS, 256, 0, stream>>>(ei, gbhist);
  k_bscan <<<1, 256, 0, stream>>>(gbhist, bucket_base, bucket_cursor, rowstart);
  k_bin   <<<BIN_BLOCKS, 256, 0, stream>>>(ei, bucket_cursor, ebuf);
  k_sort  <<<NBKT, 256, 0, stream>>>(ebuf, bucket_base, srcs, rowstart, dinv);

  const int GB = (NN + 127)/128;     // 782
  const int AB = NN/8;               // 12500

  // ---- layer 1 ----
  k_gemm<0><<<GB, 256, 0, stream>>>(x, wT, gbuf, dinv, batch, nullptr, nullptr, nullptr, nullptr);
  k_agg<<<AB, 256, 0, stream>>>(gbuf, rowstart, srcs, dinv, b1, batch, bufB, S1, S2);
  k_finalize<<<(NG*HD+255)/256, 256, 0, stream>>>(S1, S2, gstart, g1a, am_tab, rs_tab);

  // ---- layer 2 ----
  k_gemm<1><<<GB, 256, 0, stream>>>(bufB, wT + 16384, gbuf, dinv, batch, g1w, g1b, am_tab, rs_tab);
  k_agg<<<AB, 256, 0, stream>>>(gbuf, rowstart, srcs, dinv, b2, batch, bufB, S1, S2);
  k_finalize<<<(NG*HD+255)/256, 256, 0, stream>>>(S1, S2, gstart, g2a, am_tab, rs_tab);

  // ---- layer 3 ----
  k_gemm<1><<<GB, 256, 0, stream>>>(bufB, wT + 32768, gbuf, dinv, batch, g2w, g2b, am_tab, rs_tab);
  k_agg<<<AB, 256, 0, stream>>>(gbuf, rowstart, srcs, dinv, b3, batch, bufB, S1, S2);
  k_finalize<<<(NG*HD+255)/256, 256, 0, stream>>>(S1, S2, gstart, g3a, am_tab, rs_tab);

  // ---- pool + head ----
  k_poolhead<<<NG, 256, 0, stream>>>(bufB, gstart, g3w, g3b, am_tab, rs_tab, lw, lb, out);
}

// Round 5
// 491.514 us; speedup vs baseline: 1.4214x; 1.4214x over previous
//
#include <hip/hip_runtime.h>

#define NN 100000
#define NE 1600000
#define HD 128
#define NG 128
#define NC 10
#define EPSV 1e-5f

#define BSH 9                      // 512 dst nodes per bucket
#define NBKT ((NN + 511) >> 9)     // 196
#define BIN_BLOCKS ((NE + 4095) / 4096)  // 391

typedef __attribute__((ext_vector_type(8))) short short8;
typedef __attribute__((ext_vector_type(4))) float f32x4;

__device__ __forceinline__ float b2f(ushort u){ return __uint_as_float(((unsigned)u)<<16); }
__device__ __forceinline__ ushort f2b(float f){
  unsigned u = __float_as_uint(f);
  unsigned r = (u + 0x7FFFu + ((u>>16)&1u)) >> 16;   // RNE
  return (ushort)r;
}

// ---------------- init: granges + weight-prep + zeroing ----------------
__global__ __launch_bounds__(256)
void k_init(const int* __restrict__ batch, int* __restrict__ gstart,
            const float* __restrict__ w1, const float* __restrict__ w2,
            const float* __restrict__ w3, ushort* __restrict__ wT,
            int* __restrict__ gbhist, float* __restrict__ s12_base)
{
  int b = blockIdx.x, t = threadIdx.x;
  if(b < 391){                       // granges: batch sorted -> contiguous segments
    int n = b*256 + t;
    if(n >= NN) return;
    int bb = batch[n];
    if(n == 0){
      for(int g=0; g<=bb; g++) gstart[g] = 0;
      int last = batch[NN-1];
      for(int g=last+1; g<=NG; g++) gstart[g] = NN;
    } else {
      int bp = batch[n-1];
      for(int g=bp+1; g<=bb; g++) gstart[g] = n;
    }
  } else if(b < 394){                // wT[layer][h][k] = bf16(w[k][h])
    const float* w = (b == 391) ? w1 : (b == 392) ? w2 : w3;
    ushort* o = wT + (b-391)*16384;
    #pragma unroll 4
    for(int i=0;i<64;i++){
      int e = i*256 + t;
      int k = e>>7, h = e&127;
      o[h*128 + k] = f2b(w[e]);
    }
  } else if(b < 398){                // zero S1+S2 (contiguous 32768 floats)
    #pragma unroll 8
    for(int i=0;i<32;i++) s12_base[(b-394)*8192 + i*256 + t] = 0.f;
  } else {                           // zero gbhist
    if(t < NBKT) gbhist[t] = 0;
  }
}

// ---------------- pass 0: global bucket histogram ----------------
__global__ __launch_bounds__(256) void k_bhist(const int* __restrict__ ei, int* __restrict__ gbhist){
  __shared__ int h[NBKT];
  int t = threadIdx.x;
  if(t < NBKT) h[t] = 0;
  __syncthreads();
  int base = blockIdx.x*4096;
  #pragma unroll
  for(int i=0;i<16;i++){
    int e = base + i*256 + t;
    if(e < NE) atomicAdd(&h[ei[NE + e] >> BSH], 1);
  }
  __syncthreads();
  if(t < NBKT && h[t]) atomicAdd(&gbhist[t], h[t]);
}

__global__ void k_bscan(const int* __restrict__ gbhist, int* __restrict__ bucket_base,
                        int* __restrict__ bucket_cursor, int* __restrict__ rowstart){
  __shared__ int lds[256];
  int t = threadIdx.x;
  int v = (t < NBKT) ? gbhist[t] : 0;
  lds[t] = v; __syncthreads();
  for(int off=1; off<256; off<<=1){
    int y = lds[t]; int z = (t>=off)?lds[t-off]:0;
    __syncthreads(); lds[t] = y+z; __syncthreads();
  }
  int excl = (t>0)?lds[t-1]:0;
  if(t < NBKT){ bucket_base[t] = excl; bucket_cursor[t] = excl; }
  if(t == 0){ bucket_base[NBKT] = NE; rowstart[NN] = NE; }
}

// ---------------- pass 1: bin edges by dst bucket (LDS-staged, contiguous writes) ----------
__global__ __launch_bounds__(256) void k_bin(const int* __restrict__ ei, int* __restrict__ bucket_cursor,
                                             unsigned long long* __restrict__ ebuf){
  __shared__ unsigned long long eb[4096];
  __shared__ int hist[NBKT], lstart[NBKT], lcur[NBKT], rbase[NBKT];
  __shared__ int scanbuf[256];
  int t = threadIdx.x;
  if(t < NBKT) hist[t] = 0;
  __syncthreads();
  int base = blockIdx.x*4096;
  int nv = NE - base; if(nv > 4096) nv = 4096;
  int se[16], de[16];
  #pragma unroll
  for(int i=0;i<16;i++){
    int e = base + i*256 + t;
    if(e < NE){ se[i] = ei[e]; de[i] = ei[NE + e]; atomicAdd(&hist[de[i] >> BSH], 1); }
  }
  __syncthreads();
  int v = (t < NBKT) ? hist[t] : 0;
  scanbuf[t] = v; __syncthreads();
  for(int off=1; off<256; off<<=1){
    int y = scanbuf[t]; int z = (t>=off)?scanbuf[t-off]:0;
    __syncthreads(); scanbuf[t] = y+z; __syncthreads();
  }
  if(t < NBKT){
    int excl = (t>0)?scanbuf[t-1]:0;
    lstart[t] = excl; lcur[t] = excl;
    if(hist[t]) rbase[t] = atomicAdd(&bucket_cursor[t], hist[t]);
  }
  __syncthreads();
  #pragma unroll
  for(int i=0;i<16;i++){
    int e = base + i*256 + t;
    if(e < NE){
      int b = de[i] >> BSH;
      int idx = atomicAdd(&lcur[b], 1);
      eb[idx] = ((unsigned long long)(unsigned)de[i] << 32) | (unsigned)se[i];
    }
  }
  __syncthreads();
  #pragma unroll
  for(int i=0;i<16;i++){
    int slot = i*256 + t;
    if(slot < nv){
      unsigned long long v8 = eb[slot];
      int b = (int)(v8 >> 32) >> BSH;
      ebuf[rbase[b] + (slot - lstart[b])] = v8;
    }
  }
}

// ---------------- pass 2: per-bucket counting sort + rowstart + dinv ----------------
__global__ __launch_bounds__(256) void k_sort(const unsigned long long* __restrict__ ebuf,
                                              const int* __restrict__ bucket_base,
                                              int* __restrict__ srcs, int* __restrict__ rowstart,
                                              float* __restrict__ dinv){
  __shared__ int hist[512], cur[512];
  __shared__ int scanbuf[256];
  int b = blockIdx.x, t = threadIdx.x;
  int e0 = bucket_base[b], e1 = bucket_base[b+1];
  hist[t] = 0; hist[t+256] = 0;
  __syncthreads();
  for(int i = e0 + t; i < e1; i += 256){
    int dl = (int)(ebuf[i] >> 32) - (b << BSH);
    atomicAdd(&hist[dl], 1);
  }
  __syncthreads();
  int s0 = hist[2*t], s1 = hist[2*t+1];
  scanbuf[t] = s0 + s1; __syncthreads();
  for(int off=1; off<256; off<<=1){
    int y = scanbuf[t]; int z = (t>=off)?scanbuf[t-off]:0;
    __syncthreads(); scanbuf[t] = y+z; __syncthreads();
  }
  int excl = (t>0)?scanbuf[t-1]:0;
  cur[2*t] = excl; cur[2*t+1] = excl + s0;
  int d0 = (b << BSH) + 2*t, d1 = d0 + 1;
  if(d0 < NN){ rowstart[d0] = e0 + excl;      dinv[d0] = rsqrtf((float)(s0 + 1)); }
  if(d1 < NN){ rowstart[d1] = e0 + excl + s0; dinv[d1] = rsqrtf((float)(s1 + 1)); }
  __syncthreads();
  for(int i = e0 + t; i < e1; i += 256){
    unsigned long long v8 = ebuf[i];
    int dl = (int)(v8 >> 32) - (b << BSH);
    int pos = e0 + atomicAdd(&cur[dl], 1);
    srcs[pos] = (int)(unsigned)v8;
  }
}

// ---------------- MFMA GEMM: g[node][h] = bf16( dinv[node] * (norm_relu(in[node]) @ w)[h] ) ----
// NORM=0: raw fp32 input (layer 1). NORM=1: bf16 input + fused GraphNorm+ReLU.
template<int NORM>
__global__ __launch_bounds__(256)
void k_gemm(const void* __restrict__ in_, const ushort* __restrict__ wT,
            ushort* __restrict__ g, const float* __restrict__ dinv,
            const int* __restrict__ batch,
            const float* __restrict__ gw, const float* __restrict__ gb,
            const float* __restrict__ am_tab, const float* __restrict__ rs_tab)
{
  __shared__ ushort lds_a[128*136];
  __shared__ float sdinv[128];
  const int t = threadIdx.x;
  const int row0 = blockIdx.x * 128;

  { // stage A tile -> bf16
    const int l = t & 31;          // 4-feat slot (f0 = 4*l)
    const int rr = t >> 5;         // 0..7
    if(t < 128){
      int node = row0 + t;
      sdinv[t] = (node < NN) ? dinv[node] : 0.f;
    }
    float4 gwv, gbv;
    if(NORM){ gwv = ((const float4*)gw)[l]; gbv = ((const float4*)gb)[l]; }
    #pragma unroll 4
    for(int rb = 0; rb < 16; rb++){
      int r = rb*8 + rr;
      int node = row0 + r;
      float4 v = make_float4(0.f,0.f,0.f,0.f);
      if(node < NN){
        if(NORM){
          ushort4 raw = ((const ushort4*)in_)[(size_t)node*32 + l];
          v = make_float4(b2f(raw.x), b2f(raw.y), b2f(raw.z), b2f(raw.w));
          int gg = batch[node];
          float4 am = ((const float4*)am_tab)[gg*32 + l];
          float4 rs = ((const float4*)rs_tab)[gg*32 + l];
          v.x = fmaxf(gwv.x*(v.x-am.x)*rs.x + gbv.x, 0.f);
          v.y = fmaxf(gwv.y*(v.y-am.y)*rs.y + gbv.y, 0.f);
          v.z = fmaxf(gwv.z*(v.z-am.z)*rs.z + gbv.z, 0.f);
          v.w = fmaxf(gwv.w*(v.w-am.w)*rs.w + gbv.w, 0.f);
        } else {
          v = ((const float4*)in_)[(size_t)node*32 + l];
        }
      }
      ushort4 b4;
      b4.x = f2b(v.x); b4.y = f2b(v.y); b4.z = f2b(v.z); b4.w = f2b(v.w);
      *(ushort4*)(lds_a + r*136 + l*4) = b4;
    }
  }
  __syncthreads();

  const int wv = t >> 6;          // wave 0..3 -> cols wv*32 .. wv*32+31
  const int l  = t & 63;
  const int lc = l & 15, lk = l >> 4;

  short8 bfrag[2][4];
  #pragma unroll
  for(int tt=0; tt<2; tt++){
    int col = wv*32 + tt*16 + lc;
    #pragma unroll
    for(int s=0; s<4; s++)
      bfrag[tt][s] = *(const short8*)(wT + col*128 + s*32 + lk*8);
  }

  f32x4 acc[8][2];
  #pragma unroll
  for(int m=0;m<8;m++){ acc[m][0] = (f32x4)0.f; acc[m][1] = (f32x4)0.f; }

  #pragma unroll
  for(int m=0; m<8; m++){
    const ushort* ap = lds_a + (m*16 + lc)*136 + lk*8;
    #pragma unroll
    for(int s=0; s<4; s++){
      short8 a = *(const short8*)(ap + s*32);
      acc[m][0] = __builtin_amdgcn_mfma_f32_16x16x32_bf16(a, bfrag[0][s], acc[m][0], 0, 0, 0);
      acc[m][1] = __builtin_amdgcn_mfma_f32_16x16x32_bf16(a, bfrag[1][s], acc[m][1], 0, 0, 0);
    }
  }

  #pragma unroll
  for(int m=0; m<8; m++){
    #pragma unroll
    for(int tt=0; tt<2; tt++){
      int colg = wv*32 + tt*16 + lc;
      #pragma unroll
      for(int r=0; r<4; r++){
        int row = m*16 + lk*4 + r;
        int node = row0 + row;
        if(node < NN)
          g[(size_t)node*128 + colg] = f2b(acc[m][tt][r] * sdinv[row]);
      }
    }
  }
}

// ---------------- lean aggregation over dst-sorted edges (bf16 gather + bf16 out) ----------
// out[n] = bf16( dinv[n]*(sum_{e->n} g[src] + g[n]) + bias )
__global__ __launch_bounds__(256)
void k_agg(const ushort* __restrict__ g, const int* __restrict__ rowstart,
           const int* __restrict__ srcs, const float* __restrict__ dinv,
           const float* __restrict__ bias, ushort* __restrict__ outp)
{
  const int lane = threadIdx.x & 31;          // 4-feat slot
  const int node = blockIdx.x*8 + (threadIdx.x >> 5);
  const int e0 = rowstart[node], e1 = rowstart[node+1];
  float ax=0.f, ay=0.f, az=0.f, aw=0.f;
  float bx=0.f, by=0.f, bz=0.f, bw=0.f;
  const ushort4* gp = (const ushort4*)g;
  int e = e0;
  for(; e+7 < e1; e += 8){                    // 8 outstanding gathers
    int si[8];
    #pragma unroll
    for(int i=0;i<8;i++) si[i] = srcs[e+i];
    ushort4 v[8];
    #pragma unroll
    for(int i=0;i<8;i++) v[i] = gp[(size_t)si[i]*32 + lane];
    #pragma unroll
    for(int i=0;i<8;i++){
      if(i&1){ bx += b2f(v[i].x); by += b2f(v[i].y); bz += b2f(v[i].z); bw += b2f(v[i].w); }
      else   { ax += b2f(v[i].x); ay += b2f(v[i].y); az += b2f(v[i].z); aw += b2f(v[i].w); }
    }
  }
  for(; e+3 < e1; e += 4){
    int si[4];
    #pragma unroll
    for(int i=0;i<4;i++) si[i] = srcs[e+i];
    ushort4 v[4];
    #pragma unroll
    for(int i=0;i<4;i++) v[i] = gp[(size_t)si[i]*32 + lane];
    #pragma unroll
    for(int i=0;i<4;i++){
      if(i&1){ bx += b2f(v[i].x); by += b2f(v[i].y); bz += b2f(v[i].z); bw += b2f(v[i].w); }
      else   { ax += b2f(v[i].x); ay += b2f(v[i].y); az += b2f(v[i].z); aw += b2f(v[i].w); }
    }
  }
  for(; e < e1; e++){
    ushort4 v = gp[(size_t)srcs[e]*32 + lane];
    ax += b2f(v.x); ay += b2f(v.y); az += b2f(v.z); aw += b2f(v.w);
  }
  ushort4 vs = gp[(size_t)node*32 + lane];
  float dv = dinv[node];
  float4 bv = ((const float4*)bias)[lane];
  ushort4 o4;
  o4.x = f2b(dv*(ax+bx+b2f(vs.x))+bv.x);
  o4.y = f2b(dv*(ay+by+b2f(vs.y))+bv.y);
  o4.z = f2b(dv*(az+bz+b2f(vs.z))+bv.z);
  o4.w = f2b(dv*(aw+bw+b2f(vs.w))+bv.w);
  ((ushort4*)outp)[(size_t)node*32 + lane] = o4;
}

// ---------------- per-graph moments from bf16 (one pass: sum x, sum x^2) ----------------
#define STAT_CH 8
__global__ __launch_bounds__(128)
void k_stats(const ushort* __restrict__ x, const int* __restrict__ gstart,
             float* __restrict__ S1, float* __restrict__ S2)
{
  int g = blockIdx.x, ch = blockIdx.y, f = threadIdx.x;
  int s = gstart[g], e = gstart[g+1];
  int len = e - s;
  int i0 = s + (int)((long long)len * ch / STAT_CH);
  int i1 = s + (int)((long long)len * (ch+1) / STAT_CH);
  float a1 = 0.f, a2 = 0.f;
  for(int n=i0; n<i1; n++){
    float v = b2f(x[(size_t)n*128 + f]);
    a1 += v; a2 += v*v;
  }
  if(i1 > i0){
    atomicAdd(&S1[g*128+f], a1);
    atomicAdd(&S2[g*128+f], a2);
  }
}

// var = E[x^2] - (2a - a^2) m^2 ; tables: am = a*m, rs = rsqrt(var+eps). Self-zeroes S1/S2.
__global__ __launch_bounds__(256)
void k_finalize(float* __restrict__ S1, float* __restrict__ S2,
                const int* __restrict__ gstart, const float* __restrict__ ga,
                float* __restrict__ am_tab, float* __restrict__ rs_tab)
{
  int i = blockIdx.x*256 + threadIdx.x;
  if(i >= NG*HD) return;
  int g = i >> 7, f = i & 127;
  int len = gstart[g+1] - gstart[g];
  float cnt = (float)(len > 0 ? len : 1);
  float inv = 1.f/cnt;
  float m = S1[i]*inv, ex2 = S2[i]*inv;
  float a = ga[f];
  float var = ex2 - (2.f*a - a*a)*m*m;
  am_tab[i] = a*m;
  rs_tab[i] = rsqrtf(var + EPSV);
  S1[i] = 0.f; S2[i] = 0.f;       // ready for next layer
}

// ---------------- fused pool + head: one block per graph ----------------
__global__ __launch_bounds__(256)
void k_poolhead(const ushort* __restrict__ x, const int* __restrict__ gstart,
                const float* __restrict__ gw, const float* __restrict__ gb,
                const float* __restrict__ am_tab, const float* __restrict__ rs_tab,
                const float* __restrict__ lw, const float* __restrict__ lb,
                float* __restrict__ out)
{
  int g = blockIdx.x, t = threadIdx.x;
  int f = t & 127, sub = t >> 7;
  int s = gstart[g], e = gstart[g+1];
  float wv = gw[f], bv = gb[f];
  float am = am_tab[g*128+f], rs = rs_tab[g*128+f];
  float a1 = 0.f;
  for(int n = s + sub; n < e; n += 2){
    float v = b2f(x[(size_t)n*128 + f]);
    v = wv*(v-am)*rs + bv;
    a1 += fmaxf(v, 0.f);
  }
  __shared__ float sh[256];
  __shared__ float lg[NC];
  __shared__ float lse_s;
  sh[t] = a1;
  __syncthreads();
  if(t < 128){
    int len = e - s;
    float inv = 1.f/(float)(len > 0 ? len : 1);
    sh[t] = (sh[t] + sh[t+128]) * inv;
  }
  __syncthreads();
  if(t < NC){
    float acc = lb[t];
    for(int f2=0; f2<128; f2++) acc += sh[f2]*lw[f2*NC + t];
    lg[t] = acc;
  }
  __syncthreads();
  if(t == 0){
    float mx = -1e30f;
    for(int c=0;c<NC;c++) mx = fmaxf(mx, lg[c]);
    float sm = 0.f;
    for(int c=0;c<NC;c++) sm += expf(lg[c]-mx);
    lse_s = mx + logf(sm);
  }
  __syncthreads();
  if(t < NC) out[g*NC + t] = lg[t] - lse_s;
}

// ---------------- launch ----------------
extern "C" void kernel_launch(void* const* d_in, const int* in_sizes, int n_in,
                              void* d_out, int out_size, void* d_ws, size_t ws_size,
                              hipStream_t stream)
{
  const float* x    = (const float*)d_in[0];
  const int*   ei   = (const int*)d_in[1];
  const int*   batch= (const int*)d_in[2];
  const float* w1   = (const float*)d_in[3];
  const float* b1   = (const float*)d_in[4];
  const float* w2   = (const float*)d_in[5];
  const float* b2   = (const float*)d_in[6];
  const float* w3   = (const float*)d_in[7];
  const float* b3   = (const float*)d_in[8];
  const float* g1w  = (const float*)d_in[9];
  const float* g1b  = (const float*)d_in[10];
  const float* g1a  = (const float*)d_in[11];
  const float* g2w  = (const float*)d_in[12];
  const float* g2b  = (const float*)d_in[13];
  const float* g2a  = (const float*)d_in[14];
  const float* g3w  = (const float*)d_in[15];
  const float* g3b  = (const float*)d_in[16];
  const float* g3a  = (const float*)d_in[17];
  const float* lw   = (const float*)d_in[18];
  const float* lb   = (const float*)d_in[19];
  float* out = (float*)d_out;

  char* p = (char*)d_ws;
  auto take = [&](size_t nbytes){ char* q = p; p += (nbytes + 255) & ~(size_t)255; return q; };
  ushort* gbuf    = (ushort*)take((size_t)NN*HD*2);
  ushort* bufB    = (ushort*)take((size_t)NN*HD*2);
  ushort* wT      = (ushort*)take((size_t)3*HD*HD*2);
  unsigned long long* ebuf = (unsigned long long*)take((size_t)NE*8);
  int*   srcs     = (int*)  take((size_t)NE*4);
  int*   rowstart = (int*)  take((size_t)(NN+1)*4);
  float* dinv     = (float*)take((size_t)NN*4);
  int*   gbhist   = (int*)  take((size_t)NBKT*4);
  int*   bucket_base   = (int*)take((size_t)(NBKT+1)*4);
  int*   bucket_cursor = (int*)take((size_t)NBKT*4);
  int*   gstart   = (int*)  take((size_t)(NG+1)*4);
  float* S1       = (float*)take((size_t)NG*HD*4);   // contiguous with S2
  float* S2       = (float*)take((size_t)NG*HD*4);
  float* am_tab   = (float*)take((size_t)NG*HD*4);
  float* rs_tab   = (float*)take((size_t)NG*HD*4);
  if((size_t)(p - (char*)d_ws) > ws_size) return;  // workspace too small: fail visibly

  k_init  <<<399, 256, 0, stream>>>(batch, gstart, w1, w2, w3, wT, gbhist, S1);
  k_bhist <<<BIN_BLOCKS, 256, 0, stream>>>(ei, gbhist);
  k_bscan <<<1, 256, 0, stream>>>(gbhist, bucket_base, bucket_cursor, rowstart);
  k_bin   <<<BIN_BLOCKS, 256, 0, stream>>>(ei, bucket_cursor, ebuf);
  k_sort  <<<NBKT, 256, 0, stream>>>(ebuf, bucket_base, srcs, rowstart, dinv);

  const int GB = (NN + 127)/128;     // 782
  const int AB = NN/8;               // 12500

  // ---- layer 1 ----
  k_gemm<0><<<GB, 256, 0, stream>>>(x, wT, gbuf, dinv, batch, nullptr, nullptr, nullptr, nullptr);
  k_agg<<<AB, 256, 0, stream>>>(gbuf, rowstart, srcs, dinv, b1, bufB);
  k_stats<<<dim3(NG, STAT_CH), 128, 0, stream>>>(bufB, gstart, S1, S2);
  k_finalize<<<(NG*HD+255)/256, 256, 0, stream>>>(S1, S2, gstart, g1a, am_tab, rs_tab);

  // ---- layer 2 ----
  k_gemm<1><<<GB, 256, 0, stream>>>(bufB, wT + 16384, gbuf, dinv, batch, g1w, g1b, am_tab, rs_tab);
  k_agg<<<AB, 256, 0, stream>>>(gbuf, rowstart, srcs, dinv, b2, bufB);
  k_stats<<<dim3(NG, STAT_CH), 128, 0, stream>>>(bufB, gstart, S1, S2);
  k_finalize<<<(NG*HD+255)/256, 256, 0, stream>>>(S1, S2, gstart, g2a, am_tab, rs_tab);

  // ---- layer 3 ----
  k_gemm<1><<<GB, 256, 0, stream>>>(bufB, wT + 32768, gbuf, dinv, batch, g2w, g2b, am_tab, rs_tab);
  k_agg<<<AB, 256, 0, stream>>>(gbuf, rowstart, srcs, dinv, b3, bufB);
  k_stats<<<dim3(NG, STAT_CH), 128, 0, stream>>>(bufB, gstart, S1, S2);
  k_finalize<<<(NG*HD+255)/256, 256, 0, stream>>>(S1, S2, gstart, g3a, am_tab, rs_tab);

  // ---- pool + head ----
  k_poolhead<<<NG, 256, 0, stream>>>(bufB, gstart, g3w, g3b, am_tab, rs_tab, lw, lb, out);
}

// Round 6
// 445.664 us; speedup vs baseline: 1.5676x; 1.1029x over previous
//
#include <hip/hip_runtime.h>

#define NN 100000
#define NE 1600000
#define HD 128
#define NG 128
#define NC 10
#define EPSV 1e-5f

#define BSH 9                      // 512 dst nodes per bucket
#define NBKT ((NN + 511) >> 9)     // 196
#define BIN_BLOCKS ((NE + 4095) / 4096)  // 391

typedef __attribute__((ext_vector_type(8))) short short8;
typedef __attribute__((ext_vector_type(4))) float f32x4;

__device__ __forceinline__ float b2f(ushort u){ return __uint_as_float(((unsigned)u)<<16); }
__device__ __forceinline__ ushort f2b(float f){
  unsigned u = __float_as_uint(f);
  unsigned r = (u + 0x7FFFu + ((u>>16)&1u)) >> 16;   // RNE
  return (ushort)r;
}

// ---------------- init: granges + weight-prep + zeroing (S1,S2,pooled contiguous) ----------
__global__ __launch_bounds__(256)
void k_init(const int* __restrict__ batch, int* __restrict__ gstart,
            const float* __restrict__ w1, const float* __restrict__ w2,
            const float* __restrict__ w3, ushort* __restrict__ wT,
            int* __restrict__ gbhist, float* __restrict__ s12_base)
{
  int b = blockIdx.x, t = threadIdx.x;
  if(b < 391){                       // granges: batch sorted -> contiguous segments
    int n = b*256 + t;
    if(n >= NN) return;
    int bb = batch[n];
    if(n == 0){
      for(int g=0; g<=bb; g++) gstart[g] = 0;
      int last = batch[NN-1];
      for(int g=last+1; g<=NG; g++) gstart[g] = NN;
    } else {
      int bp = batch[n-1];
      for(int g=bp+1; g<=bb; g++) gstart[g] = n;
    }
  } else if(b < 394){                // wT[layer][h][k] = bf16(w[k][h])
    const float* w = (b == 391) ? w1 : (b == 392) ? w2 : w3;
    ushort* o = wT + (b-391)*16384;
    #pragma unroll 4
    for(int i=0;i<64;i++){
      int e = i*256 + t;
      int k = e>>7, h = e&127;
      o[h*128 + k] = f2b(w[e]);
    }
  } else if(b < 400){                // zero S1+S2+pooled (contiguous 49152 floats)
    #pragma unroll 8
    for(int i=0;i<32;i++) s12_base[(b-394)*8192 + i*256 + t] = 0.f;
  } else {                           // zero gbhist
    if(t < NBKT) gbhist[t] = 0;
  }
}

// ---------------- pass 0: global bucket histogram ----------------
__global__ __launch_bounds__(256) void k_bhist(const int* __restrict__ ei, int* __restrict__ gbhist){
  __shared__ int h[NBKT];
  int t = threadIdx.x;
  if(t < NBKT) h[t] = 0;
  __syncthreads();
  int base = blockIdx.x*4096;
  #pragma unroll
  for(int i=0;i<16;i++){
    int e = base + i*256 + t;
    if(e < NE) atomicAdd(&h[ei[NE + e] >> BSH], 1);
  }
  __syncthreads();
  if(t < NBKT && h[t]) atomicAdd(&gbhist[t], h[t]);
}

__global__ void k_bscan(const int* __restrict__ gbhist, int* __restrict__ bucket_base,
                        int* __restrict__ bucket_cursor, int* __restrict__ rowstart){
  __shared__ int lds[256];
  int t = threadIdx.x;
  int v = (t < NBKT) ? gbhist[t] : 0;
  lds[t] = v; __syncthreads();
  for(int off=1; off<256; off<<=1){
    int y = lds[t]; int z = (t>=off)?lds[t-off]:0;
    __syncthreads(); lds[t] = y+z; __syncthreads();
  }
  int excl = (t>0)?lds[t-1]:0;
  if(t < NBKT){ bucket_base[t] = excl; bucket_cursor[t] = excl; }
  if(t == 0){ bucket_base[NBKT] = NE; rowstart[NN] = NE; }
}

// ---------------- pass 1: bin edges by dst bucket (LDS-staged, contiguous writes) ----------
__global__ __launch_bounds__(256) void k_bin(const int* __restrict__ ei, int* __restrict__ bucket_cursor,
                                             unsigned long long* __restrict__ ebuf){
  __shared__ unsigned long long eb[4096];
  __shared__ int hist[NBKT], lstart[NBKT], lcur[NBKT], rbase[NBKT];
  __shared__ int scanbuf[256];
  int t = threadIdx.x;
  if(t < NBKT) hist[t] = 0;
  __syncthreads();
  int base = blockIdx.x*4096;
  int nv = NE - base; if(nv > 4096) nv = 4096;
  int se[16], de[16];
  #pragma unroll
  for(int i=0;i<16;i++){
    int e = base + i*256 + t;
    if(e < NE){ se[i] = ei[e]; de[i] = ei[NE + e]; atomicAdd(&hist[de[i] >> BSH], 1); }
  }
  __syncthreads();
  int v = (t < NBKT) ? hist[t] : 0;
  scanbuf[t] = v; __syncthreads();
  for(int off=1; off<256; off<<=1){
    int y = scanbuf[t]; int z = (t>=off)?scanbuf[t-off]:0;
    __syncthreads(); scanbuf[t] = y+z; __syncthreads();
  }
  if(t < NBKT){
    int excl = (t>0)?scanbuf[t-1]:0;
    lstart[t] = excl; lcur[t] = excl;
    if(hist[t]) rbase[t] = atomicAdd(&bucket_cursor[t], hist[t]);
  }
  __syncthreads();
  #pragma unroll
  for(int i=0;i<16;i++){
    int e = base + i*256 + t;
    if(e < NE){
      int b = de[i] >> BSH;
      int idx = atomicAdd(&lcur[b], 1);
      eb[idx] = ((unsigned long long)(unsigned)de[i] << 32) | (unsigned)se[i];
    }
  }
  __syncthreads();
  #pragma unroll
  for(int i=0;i<16;i++){
    int slot = i*256 + t;
    if(slot < nv){
      unsigned long long v8 = eb[slot];
      int b = (int)(v8 >> 32) >> BSH;
      ebuf[rbase[b] + (slot - lstart[b])] = v8;
    }
  }
}

// ---------------- pass 2: per-bucket counting sort + rowstart + dinv ----------------
__global__ __launch_bounds__(256) void k_sort(const unsigned long long* __restrict__ ebuf,
                                              const int* __restrict__ bucket_base,
                                              int* __restrict__ srcs, int* __restrict__ rowstart,
                                              float* __restrict__ dinv){
  __shared__ int hist[512], cur[512];
  __shared__ int scanbuf[256];
  int b = blockIdx.x, t = threadIdx.x;
  int e0 = bucket_base[b], e1 = bucket_base[b+1];
  hist[t] = 0; hist[t+256] = 0;
  __syncthreads();
  for(int i = e0 + t; i < e1; i += 256){
    int dl = (int)(ebuf[i] >> 32) - (b << BSH);
    atomicAdd(&hist[dl], 1);
  }
  __syncthreads();
  int s0 = hist[2*t], s1 = hist[2*t+1];
  scanbuf[t] = s0 + s1; __syncthreads();
  for(int off=1; off<256; off<<=1){
    int y = scanbuf[t]; int z = (t>=off)?scanbuf[t-off]:0;
    __syncthreads(); scanbuf[t] = y+z; __syncthreads();
  }
  int excl = (t>0)?scanbuf[t-1]:0;
  cur[2*t] = excl; cur[2*t+1] = excl + s0;
  int d0 = (b << BSH) + 2*t, d1 = d0 + 1;
  if(d0 < NN){ rowstart[d0] = e0 + excl;      dinv[d0] = rsqrtf((float)(s0 + 1)); }
  if(d1 < NN){ rowstart[d1] = e0 + excl + s0; dinv[d1] = rsqrtf((float)(s1 + 1)); }
  __syncthreads();
  for(int i = e0 + t; i < e1; i += 256){
    unsigned long long v8 = ebuf[i];
    int dl = (int)(v8 >> 32) - (b << BSH);
    int pos = e0 + atomicAdd(&cur[dl], 1);
    srcs[pos] = (int)(unsigned)v8;
  }
}

// ---------------- MFMA GEMM: g[node][h] = bf16( dinv[node] * (norm_relu(in[node]) @ w)[h] ) ----
// NORM=0: raw fp32 input (layer 1). NORM=1: bf16 input + fused GraphNorm+ReLU.
template<int NORM>
__global__ __launch_bounds__(256)
void k_gemm(const void* __restrict__ in_, const ushort* __restrict__ wT,
            ushort* __restrict__ g, const float* __restrict__ dinv,
            const int* __restrict__ batch,
            const float* __restrict__ gw, const float* __restrict__ gb,
            const float* __restrict__ am_tab, const float* __restrict__ rs_tab)
{
  __shared__ ushort lds_a[128*136];
  __shared__ float sdinv[128];
  const int t = threadIdx.x;
  const int row0 = blockIdx.x * 128;

  { // stage A tile -> bf16
    const int l = t & 31;          // 4-feat slot (f0 = 4*l)
    const int rr = t >> 5;         // 0..7
    if(t < 128){
      int node = row0 + t;
      sdinv[t] = (node < NN) ? dinv[node] : 0.f;
    }
    float4 gwv, gbv;
    if(NORM){ gwv = ((const float4*)gw)[l]; gbv = ((const float4*)gb)[l]; }
    #pragma unroll 4
    for(int rb = 0; rb < 16; rb++){
      int r = rb*8 + rr;
      int node = row0 + r;
      float4 v = make_float4(0.f,0.f,0.f,0.f);
      if(node < NN){
        if(NORM){
          ushort4 raw = ((const ushort4*)in_)[(size_t)node*32 + l];
          v = make_float4(b2f(raw.x), b2f(raw.y), b2f(raw.z), b2f(raw.w));
          int gg = batch[node];
          float4 am = ((const float4*)am_tab)[gg*32 + l];
          float4 rs = ((const float4*)rs_tab)[gg*32 + l];
          v.x = fmaxf(gwv.x*(v.x-am.x)*rs.x + gbv.x, 0.f);
          v.y = fmaxf(gwv.y*(v.y-am.y)*rs.y + gbv.y, 0.f);
          v.z = fmaxf(gwv.z*(v.z-am.z)*rs.z + gbv.z, 0.f);
          v.w = fmaxf(gwv.w*(v.w-am.w)*rs.w + gbv.w, 0.f);
        } else {
          v = ((const float4*)in_)[(size_t)node*32 + l];
        }
      }
      ushort4 b4;
      b4.x = f2b(v.x); b4.y = f2b(v.y); b4.z = f2b(v.z); b4.w = f2b(v.w);
      *(ushort4*)(lds_a + r*136 + l*4) = b4;
    }
  }
  __syncthreads();

  const int wv = t >> 6;          // wave 0..3 -> cols wv*32 .. wv*32+31
  const int l  = t & 63;
  const int lc = l & 15, lk = l >> 4;

  short8 bfrag[2][4];
  #pragma unroll
  for(int tt=0; tt<2; tt++){
    int col = wv*32 + tt*16 + lc;
    #pragma unroll
    for(int s=0; s<4; s++)
      bfrag[tt][s] = *(const short8*)(wT + col*128 + s*32 + lk*8);
  }

  f32x4 acc[8][2];
  #pragma unroll
  for(int m=0;m<8;m++){ acc[m][0] = (f32x4)0.f; acc[m][1] = (f32x4)0.f; }

  #pragma unroll
  for(int m=0; m<8; m++){
    const ushort* ap = lds_a + (m*16 + lc)*136 + lk*8;
    #pragma unroll
    for(int s=0; s<4; s++){
      short8 a = *(const short8*)(ap + s*32);
      acc[m][0] = __builtin_amdgcn_mfma_f32_16x16x32_bf16(a, bfrag[0][s], acc[m][0], 0, 0, 0);
      acc[m][1] = __builtin_amdgcn_mfma_f32_16x16x32_bf16(a, bfrag[1][s], acc[m][1], 0, 0, 0);
    }
  }

  #pragma unroll
  for(int m=0; m<8; m++){
    #pragma unroll
    for(int tt=0; tt<2; tt++){
      int colg = wv*32 + tt*16 + lc;
      #pragma unroll
      for(int r=0; r<4; r++){
        int row = m*16 + lk*4 + r;
        int node = row0 + row;
        if(node < NN)
          g[(size_t)node*128 + colg] = f2b(acc[m][tt][r] * sdinv[row]);
      }
    }
  }
}

// ---------------- lean aggregation over dst-sorted edges (bf16 gather + bf16 out) ----------
// out[n] = bf16( dinv[n]*(sum_{e->n} g[src] + g[n]) + bias )
__global__ __launch_bounds__(256)
void k_agg(const ushort* __restrict__ g, const int* __restrict__ rowstart,
           const int* __restrict__ srcs, const float* __restrict__ dinv,
           const float* __restrict__ bias, ushort* __restrict__ outp)
{
  const int lane = threadIdx.x & 31;          // 4-feat slot
  const int node = blockIdx.x*8 + (threadIdx.x >> 5);
  const int e0 = rowstart[node], e1 = rowstart[node+1];
  float ax=0.f, ay=0.f, az=0.f, aw=0.f;
  float bx=0.f, by=0.f, bz=0.f, bw=0.f;
  const ushort4* gp = (const ushort4*)g;
  int e = e0;
  for(; e+7 < e1; e += 8){                    // 8 outstanding gathers
    int si[8];
    #pragma unroll
    for(int i=0;i<8;i++) si[i] = srcs[e+i];
    ushort4 v[8];
    #pragma unroll
    for(int i=0;i<8;i++) v[i] = gp[(size_t)si[i]*32 + lane];
    #pragma unroll
    for(int i=0;i<8;i++){
      if(i&1){ bx += b2f(v[i].x); by += b2f(v[i].y); bz += b2f(v[i].z); bw += b2f(v[i].w); }
      else   { ax += b2f(v[i].x); ay += b2f(v[i].y); az += b2f(v[i].z); aw += b2f(v[i].w); }
    }
  }
  for(; e+3 < e1; e += 4){
    int si[4];
    #pragma unroll
    for(int i=0;i<4;i++) si[i] = srcs[e+i];
    ushort4 v[4];
    #pragma unroll
    for(int i=0;i<4;i++) v[i] = gp[(size_t)si[i]*32 + lane];
    #pragma unroll
    for(int i=0;i<4;i++){
      if(i&1){ bx += b2f(v[i].x); by += b2f(v[i].y); bz += b2f(v[i].z); bw += b2f(v[i].w); }
      else   { ax += b2f(v[i].x); ay += b2f(v[i].y); az += b2f(v[i].z); aw += b2f(v[i].w); }
    }
  }
  for(; e < e1; e++){
    ushort4 v = gp[(size_t)srcs[e]*32 + lane];
    ax += b2f(v.x); ay += b2f(v.y); az += b2f(v.z); aw += b2f(v.w);
  }
  ushort4 vs = gp[(size_t)node*32 + lane];
  float dv = dinv[node];
  float4 bv = ((const float4*)bias)[lane];
  ushort4 o4;
  o4.x = f2b(dv*(ax+bx+b2f(vs.x))+bv.x);
  o4.y = f2b(dv*(ay+by+b2f(vs.y))+bv.y);
  o4.z = f2b(dv*(az+bz+b2f(vs.z))+bv.z);
  o4.w = f2b(dv*(aw+bw+b2f(vs.w))+bv.w);
  ((ushort4*)outp)[(size_t)node*32 + lane] = o4;
}

// ---------------- per-graph moments from bf16 (one pass: sum x, sum x^2) ----------------
#define STAT_CH 8
__global__ __launch_bounds__(128)
void k_stats(const ushort* __restrict__ x, const int* __restrict__ gstart,
             float* __restrict__ S1, float* __restrict__ S2)
{
  int g = blockIdx.x, ch = blockIdx.y, f = threadIdx.x;
  int s = gstart[g], e = gstart[g+1];
  int len = e - s;
  int i0 = s + (int)((long long)len * ch / STAT_CH);
  int i1 = s + (int)((long long)len * (ch+1) / STAT_CH);
  float a1 = 0.f, a2 = 0.f;
  for(int n=i0; n<i1; n++){
    float v = b2f(x[(size_t)n*128 + f]);
    a1 += v; a2 += v*v;
  }
  if(i1 > i0){
    atomicAdd(&S1[g*128+f], a1);
    atomicAdd(&S2[g*128+f], a2);
  }
}

// var = E[x^2] - (2a - a^2) m^2 ; tables: am = a*m, rs = rsqrt(var+eps). Self-zeroes S1/S2.
__global__ __launch_bounds__(256)
void k_finalize(float* __restrict__ S1, float* __restrict__ S2,
                const int* __restrict__ gstart, const float* __restrict__ ga,
                float* __restrict__ am_tab, float* __restrict__ rs_tab)
{
  int i = blockIdx.x*256 + threadIdx.x;
  if(i >= NG*HD) return;
  int g = i >> 7, f = i & 127;
  int len = gstart[g+1] - gstart[g];
  float cnt = (float)(len > 0 ? len : 1);
  float inv = 1.f/cnt;
  float m = S1[i]*inv, ex2 = S2[i]*inv;
  float a = ga[f];
  float var = ex2 - (2.f*a - a*a)*m*m;
  am_tab[i] = a*m;
  rs_tab[i] = rsqrtf(var + EPSV);
  S1[i] = 0.f; S2[i] = 0.f;       // ready for next layer
}

// ---------------- pooled[g][f] += sum_n relu(norm3(x[n][f]))  (16-way split per graph) ------
#define POOL_CH 16
__global__ __launch_bounds__(128)
void k_pool(const ushort* __restrict__ x, const int* __restrict__ gstart,
            const float* __restrict__ gw, const float* __restrict__ gb,
            const float* __restrict__ am_tab, const float* __restrict__ rs_tab,
            float* __restrict__ pooled)
{
  int g = blockIdx.x, ch = blockIdx.y, f = threadIdx.x;
  int s = gstart[g], e = gstart[g+1];
  int len = e - s;
  int i0 = s + (int)((long long)len * ch / POOL_CH);
  int i1 = s + (int)((long long)len * (ch+1) / POOL_CH);
  float wv = gw[f], bv = gb[f];
  float am = am_tab[g*128+f], rs = rs_tab[g*128+f];
  float a1 = 0.f;
  for(int n=i0; n<i1; n++){
    float v = b2f(x[(size_t)n*128 + f]);
    v = wv*(v-am)*rs + bv;
    a1 += fmaxf(v, 0.f);
  }
  if(i1 > i0) atomicAdd(&pooled[g*128+f], a1);
}

// ---------------- head: logits = pooled/cnt @ lw + lb, log_softmax ----------------
__global__ __launch_bounds__(64)
void k_head(const float* __restrict__ pooled, const int* __restrict__ gstart,
            const float* __restrict__ lw, const float* __restrict__ lb,
            float* __restrict__ out)
{
  int g = blockIdx.x, t = threadIdx.x;
  __shared__ float lg[NC];
  __shared__ float lse_s;
  int len = gstart[g+1] - gstart[g];
  float inv = 1.f/(float)(len > 0 ? len : 1);
  if(t < NC){
    float acc = lb[t];
    for(int f=0; f<128; f++) acc += pooled[g*128+f]*inv*lw[f*NC + t];
    lg[t] = acc;
  }
  __syncthreads();
  if(t == 0){
    float mx = -1e30f;
    for(int c=0;c<NC;c++) mx = fmaxf(mx, lg[c]);
    float sm = 0.f;
    for(int c=0;c<NC;c++) sm += expf(lg[c]-mx);
    lse_s = mx + logf(sm);
  }
  __syncthreads();
  if(t < NC) out[g*NC + t] = lg[t] - lse_s;
}

// ---------------- launch ----------------
extern "C" void kernel_launch(void* const* d_in, const int* in_sizes, int n_in,
                              void* d_out, int out_size, void* d_ws, size_t ws_size,
                              hipStream_t stream)
{
  const float* x    = (const float*)d_in[0];
  const int*   ei   = (const int*)d_in[1];
  const int*   batch= (const int*)d_in[2];
  const float* w1   = (const float*)d_in[3];
  const float* b1   = (const float*)d_in[4];
  const float* w2   = (const float*)d_in[5];
  const float* b2   = (const float*)d_in[6];
  const float* w3   = (const float*)d_in[7];
  const float* b3   = (const float*)d_in[8];
  const float* g1w  = (const float*)d_in[9];
  const float* g1b  = (const float*)d_in[10];
  const float* g1a  = (const float*)d_in[11];
  const float* g2w  = (const float*)d_in[12];
  const float* g2b  = (const float*)d_in[13];
  const float* g2a  = (const float*)d_in[14];
  const float* g3w  = (const float*)d_in[15];
  const float* g3b  = (const float*)d_in[16];
  const float* g3a  = (const float*)d_in[17];
  const float* lw   = (const float*)d_in[18];
  const float* lb   = (const float*)d_in[19];
  float* out = (float*)d_out;

  char* p = (char*)d_ws;
  auto take = [&](size_t nbytes){ char* q = p; p += (nbytes + 255) & ~(size_t)255; return q; };
  ushort* gbuf    = (ushort*)take((size_t)NN*HD*2);
  ushort* bufB    = (ushort*)take((size_t)NN*HD*2);
  ushort* wT      = (ushort*)take((size_t)3*HD*HD*2);
  unsigned long long* ebuf = (unsigned long long*)take((size_t)NE*8);
  int*   srcs     = (int*)  take((size_t)NE*4);
  int*   rowstart = (int*)  take((size_t)(NN+1)*4);
  float* dinv     = (float*)take((size_t)NN*4);
  int*   gbhist   = (int*)  take((size_t)NBKT*4);
  int*   bucket_base   = (int*)take((size_t)(NBKT+1)*4);
  int*   bucket_cursor = (int*)take((size_t)NBKT*4);
  int*   gstart   = (int*)  take((size_t)(NG+1)*4);
  float* S1       = (float*)take((size_t)NG*HD*4);   // S1,S2,pooled contiguous (zeroed together)
  float* S2       = (float*)take((size_t)NG*HD*4);
  float* pooled   = (float*)take((size_t)NG*HD*4);
  float* am_tab   = (float*)take((size_t)NG*HD*4);
  float* rs_tab   = (float*)take((size_t)NG*HD*4);
  if((size_t)(p - (char*)d_ws) > ws_size) return;  // workspace too small: fail visibly

  k_init  <<<401, 256, 0, stream>>>(batch, gstart, w1, w2, w3, wT, gbhist, S1);
  k_bhist <<<BIN_BLOCKS, 256, 0, stream>>>(ei, gbhist);
  k_bscan <<<1, 256, 0, stream>>>(gbhist, bucket_base, bucket_cursor, rowstart);
  k_bin   <<<BIN_BLOCKS, 256, 0, stream>>>(ei, bucket_cursor, ebuf);
  k_sort  <<<NBKT, 256, 0, stream>>>(ebuf, bucket_base, srcs, rowstart, dinv);

  const int GB = (NN + 127)/128;     // 782
  const int AB = NN/8;               // 12500

  // ---- layer 1 ----
  k_gemm<0><<<GB, 256, 0, stream>>>(x, wT, gbuf, dinv, batch, nullptr, nullptr, nullptr, nullptr);
  k_agg<<<AB, 256, 0, stream>>>(gbuf, rowstart, srcs, dinv, b1, bufB);
  k_stats<<<dim3(NG, STAT_CH), 128, 0, stream>>>(bufB, gstart, S1, S2);
  k_finalize<<<(NG*HD+255)/256, 256, 0, stream>>>(S1, S2, gstart, g1a, am_tab, rs_tab);

  // ---- layer 2 ----
  k_gemm<1><<<GB, 256, 0, stream>>>(bufB, wT + 16384, gbuf, dinv, batch, g1w, g1b, am_tab, rs_tab);
  k_agg<<<AB, 256, 0, stream>>>(gbuf, rowstart, srcs, dinv, b2, bufB);
  k_stats<<<dim3(NG, STAT_CH), 128, 0, stream>>>(bufB, gstart, S1, S2);
  k_finalize<<<(NG*HD+255)/256, 256, 0, stream>>>(S1, S2, gstart, g2a, am_tab, rs_tab);

  // ---- layer 3 ----
  k_gemm<1><<<GB, 256, 0, stream>>>(bufB, wT + 32768, gbuf, dinv, batch, g2w, g2b, am_tab, rs_tab);
  k_agg<<<AB, 256, 0, stream>>>(gbuf, rowstart, srcs, dinv, b3, bufB);
  k_stats<<<dim3(NG, STAT_CH), 128, 0, stream>>>(bufB, gstart, S1, S2);
  k_finalize<<<(NG*HD+255)/256, 256, 0, stream>>>(S1, S2, gstart, g3a, am_tab, rs_tab);

  // ---- pool + head ----
  k_pool<<<dim3(NG, POOL_CH), 128, 0, stream>>>(bufB, gstart, g3w, g3b, am_tab, rs_tab, pooled);
  k_head<<<NG, 64, 0, stream>>>(pooled, gstart, lw, lb, out);
}

// Round 7
// 436.531 us; speedup vs baseline: 1.6004x; 1.0209x over previous
//
#include <hip/hip_runtime.h>

#define NN 100000
#define NE 1600000
#define HD 128
#define NG 128
#define NC 10
#define EPSV 1e-5f

#define BSH 9                      // 512 dst nodes per bucket
#define NBKT ((NN + 511) >> 9)     // 196
#define BIN_BLOCKS ((NE + 4095) / 4096)  // 391

typedef __attribute__((ext_vector_type(8))) short short8;
typedef __attribute__((ext_vector_type(4))) float f32x4;

__device__ __forceinline__ float b2f(ushort u){ return __uint_as_float(((unsigned)u)<<16); }
__device__ __forceinline__ ushort f2b(float f){
  unsigned u = __float_as_uint(f);
  unsigned r = (u + 0x7FFFu + ((u>>16)&1u)) >> 16;   // RNE
  return (ushort)r;
}

// ---------------- init: granges + weight-prep + zeroing (3x S1S2 + pooled + gbhist) --------
// blocks 0..390: granges | 391..393: wT | 394..407: zero 458KB | 408: gbhist
__global__ __launch_bounds__(256)
void k_init(const int* __restrict__ batch, int* __restrict__ gstart,
            const float* __restrict__ w1, const float* __restrict__ w2,
            const float* __restrict__ w3, ushort* __restrict__ wT,
            int* __restrict__ gbhist, float* __restrict__ zero_base)
{
  int b = blockIdx.x, t = threadIdx.x;
  if(b < 391){                       // granges: batch sorted -> contiguous segments
    int n = b*256 + t;
    if(n >= NN) return;
    int bb = batch[n];
    if(n == 0){
      for(int g=0; g<=bb; g++) gstart[g] = 0;
      int last = batch[NN-1];
      for(int g=last+1; g<=NG; g++) gstart[g] = NN;
    } else {
      int bp = batch[n-1];
      for(int g=bp+1; g<=bb; g++) gstart[g] = n;
    }
  } else if(b < 394){                // wT[layer][h][k] = bf16(w[k][h])
    const float* w = (b == 391) ? w1 : (b == 392) ? w2 : w3;
    ushort* o = wT + (b-391)*16384;
    #pragma unroll 4
    for(int i=0;i<64;i++){
      int e = i*256 + t;
      int k = e>>7, h = e&127;
      o[h*128 + k] = f2b(w[e]);
    }
  } else if(b < 408){                // zero 3x(S1,S2) + pooled = 114688 floats
    #pragma unroll 8
    for(int i=0;i<32;i++) zero_base[(size_t)(b-394)*8192 + i*256 + t] = 0.f;
  } else {                           // zero gbhist
    if(t < NBKT) gbhist[t] = 0;
  }
}

// ---------------- pass 0: global bucket histogram ----------------
__global__ __launch_bounds__(256) void k_bhist(const int* __restrict__ ei, int* __restrict__ gbhist){
  __shared__ int h[NBKT];
  int t = threadIdx.x;
  if(t < NBKT) h[t] = 0;
  __syncthreads();
  int base = blockIdx.x*4096;
  #pragma unroll
  for(int i=0;i<16;i++){
    int e = base + i*256 + t;
    if(e < NE) atomicAdd(&h[ei[NE + e] >> BSH], 1);
  }
  __syncthreads();
  if(t < NBKT && h[t]) atomicAdd(&gbhist[t], h[t]);
}

__global__ void k_bscan(const int* __restrict__ gbhist, int* __restrict__ bucket_base,
                        int* __restrict__ bucket_cursor, int* __restrict__ rowstart){
  __shared__ int lds[256];
  int t = threadIdx.x;
  int v = (t < NBKT) ? gbhist[t] : 0;
  lds[t] = v; __syncthreads();
  for(int off=1; off<256; off<<=1){
    int y = lds[t]; int z = (t>=off)?lds[t-off]:0;
    __syncthreads(); lds[t] = y+z; __syncthreads();
  }
  int excl = (t>0)?lds[t-1]:0;
  if(t < NBKT){ bucket_base[t] = excl; bucket_cursor[t] = excl; }
  if(t == 0){ bucket_base[NBKT] = NE; rowstart[NN] = NE; }
}

// ---------------- pass 1: bin edges by dst bucket; packed (dl<<17|src) 32-bit records -------
__global__ __launch_bounds__(256) void k_bin(const int* __restrict__ ei, int* __restrict__ bucket_cursor,
                                             unsigned* __restrict__ ebuf){
  __shared__ unsigned eb[4096];
  __shared__ unsigned char bb4[4096];
  __shared__ int hist[NBKT], lstart[NBKT], lcur[NBKT], rbase[NBKT];
  __shared__ int scanbuf[256];
  int t = threadIdx.x;
  if(t < NBKT) hist[t] = 0;
  __syncthreads();
  int base = blockIdx.x*4096;
  int nv = NE - base; if(nv > 4096) nv = 4096;
  int se[16], de[16];
  #pragma unroll
  for(int i=0;i<16;i++){
    int e = base + i*256 + t;
    if(e < NE){ se[i] = ei[e]; de[i] = ei[NE + e]; atomicAdd(&hist[de[i] >> BSH], 1); }
  }
  __syncthreads();
  int v = (t < NBKT) ? hist[t] : 0;
  scanbuf[t] = v; __syncthreads();
  for(int off=1; off<256; off<<=1){
    int y = scanbuf[t]; int z = (t>=off)?scanbuf[t-off]:0;
    __syncthreads(); scanbuf[t] = y+z; __syncthreads();
  }
  if(t < NBKT){
    int excl = (t>0)?scanbuf[t-1]:0;
    lstart[t] = excl; lcur[t] = excl;
    if(hist[t]) rbase[t] = atomicAdd(&bucket_cursor[t], hist[t]);
  }
  __syncthreads();
  #pragma unroll
  for(int i=0;i<16;i++){
    int e = base + i*256 + t;
    if(e < NE){
      int b = de[i] >> BSH;
      int idx = atomicAdd(&lcur[b], 1);
      eb[idx] = ((unsigned)(de[i] & 511) << 17) | (unsigned)se[i];
      bb4[idx] = (unsigned char)b;
    }
  }
  __syncthreads();
  #pragma unroll
  for(int i=0;i<16;i++){
    int slot = i*256 + t;
    if(slot < nv){
      int b = bb4[slot];
      ebuf[rbase[b] + (slot - lstart[b])] = eb[slot];
    }
  }
}

// ---------------- pass 2: per-bucket counting sort + rowstart + dinv ----------------
__global__ __launch_bounds__(256) void k_sort(const unsigned* __restrict__ ebuf,
                                              const int* __restrict__ bucket_base,
                                              int* __restrict__ srcs, int* __restrict__ rowstart,
                                              float* __restrict__ dinv){
  __shared__ int hist[512], cur[512];
  __shared__ int scanbuf[256];
  int b = blockIdx.x, t = threadIdx.x;
  int e0 = bucket_base[b], e1 = bucket_base[b+1];
  hist[t] = 0; hist[t+256] = 0;
  __syncthreads();
  for(int i = e0 + t; i < e1; i += 256){
    atomicAdd(&hist[ebuf[i] >> 17], 1);
  }
  __syncthreads();
  int s0 = hist[2*t], s1 = hist[2*t+1];
  scanbuf[t] = s0 + s1; __syncthreads();
  for(int off=1; off<256; off<<=1){
    int y = scanbuf[t]; int z = (t>=off)?scanbuf[t-off]:0;
    __syncthreads(); scanbuf[t] = y+z; __syncthreads();
  }
  int excl = (t>0)?scanbuf[t-1]:0;
  cur[2*t] = excl; cur[2*t+1] = excl + s0;
  int d0 = (b << BSH) + 2*t, d1 = d0 + 1;
  if(d0 < NN){ rowstart[d0] = e0 + excl;      dinv[d0] = rsqrtf((float)(s0 + 1)); }
  if(d1 < NN){ rowstart[d1] = e0 + excl + s0; dinv[d1] = rsqrtf((float)(s1 + 1)); }
  __syncthreads();
  for(int i = e0 + t; i < e1; i += 256){
    unsigned pk = ebuf[i];
    int dl = pk >> 17;
    int pos = e0 + atomicAdd(&cur[dl], 1);
    srcs[pos] = (int)(pk & 0x1FFFFu);
  }
}

// ---------------- MFMA GEMM: g[node][h] = bf16( dinv[node] * (norm_relu(in[node]) @ w)[h] ) ----
// NORM=0: raw fp32 input (layer 1). NORM=1: bf16 input + GraphNorm (inline from S1/S2) + ReLU.
template<int NORM>
__global__ __launch_bounds__(256)
void k_gemm(const void* __restrict__ in_, const ushort* __restrict__ wT,
            ushort* __restrict__ g, const float* __restrict__ dinv,
            const int* __restrict__ batch,
            const float* __restrict__ gw, const float* __restrict__ gb,
            const float* __restrict__ ga, const float* __restrict__ S1,
            const float* __restrict__ S2, const int* __restrict__ gstart)
{
  __shared__ ushort lds_a[128*136];
  __shared__ float sdinv[128];
  const int t = threadIdx.x;
  const int row0 = blockIdx.x * 128;

  { // stage A tile -> bf16
    const int l = t & 31;          // 4-feat slot (f0 = 4*l)
    const int rr = t >> 5;         // 0..7
    if(t < 128){
      int node = row0 + t;
      sdinv[t] = (node < NN) ? dinv[node] : 0.f;
    }
    float4 gwv, gbv, gav;
    float4 amv = make_float4(0.f,0.f,0.f,0.f), rsv = make_float4(0.f,0.f,0.f,0.f);
    int gprev = -1;
    if(NORM){
      gwv = ((const float4*)gw)[l]; gbv = ((const float4*)gb)[l];
      gav = ((const float4*)ga)[l];
    }
    #pragma unroll 4
    for(int rb = 0; rb < 16; rb++){
      int r = rb*8 + rr;
      int node = row0 + r;
      float4 v = make_float4(0.f,0.f,0.f,0.f);
      if(node < NN){
        if(NORM){
          ushort4 raw = ((const ushort4*)in_)[(size_t)node*32 + l];
          v = make_float4(b2f(raw.x), b2f(raw.y), b2f(raw.z), b2f(raw.w));
          int gg = batch[node];
          if(gg != gprev){                    // rows span 1-3 graphs: cache am/rs per graph
            gprev = gg;
            int c0 = gstart[gg], c1 = gstart[gg+1];
            float inv = 1.f/(float)((c1-c0) > 0 ? (c1-c0) : 1);
            float4 s1v = ((const float4*)S1)[gg*32 + l];
            float4 s2v = ((const float4*)S2)[gg*32 + l];
            float m, ex2, a;
            m = s1v.x*inv; ex2 = s2v.x*inv; a = gav.x;
            amv.x = a*m; rsv.x = rsqrtf(ex2 - (2.f*a - a*a)*m*m + EPSV);
            m = s1v.y*inv; ex2 = s2v.y*inv; a = gav.y;
            amv.y = a*m; rsv.y = rsqrtf(ex2 - (2.f*a - a*a)*m*m + EPSV);
            m = s1v.z*inv; ex2 = s2v.z*inv; a = gav.z;
            amv.z = a*m; rsv.z = rsqrtf(ex2 - (2.f*a - a*a)*m*m + EPSV);
            m = s1v.w*inv; ex2 = s2v.w*inv; a = gav.w;
            amv.w = a*m; rsv.w = rsqrtf(ex2 - (2.f*a - a*a)*m*m + EPSV);
          }
          v.x = fmaxf(gwv.x*(v.x-amv.x)*rsv.x + gbv.x, 0.f);
          v.y = fmaxf(gwv.y*(v.y-amv.y)*rsv.y + gbv.y, 0.f);
          v.z = fmaxf(gwv.z*(v.z-amv.z)*rsv.z + gbv.z, 0.f);
          v.w = fmaxf(gwv.w*(v.w-amv.w)*rsv.w + gbv.w, 0.f);
        } else {
          v = ((const float4*)in_)[(size_t)node*32 + l];
        }
      }
      ushort4 b4;
      b4.x = f2b(v.x); b4.y = f2b(v.y); b4.z = f2b(v.z); b4.w = f2b(v.w);
      *(ushort4*)(lds_a + r*136 + l*4) = b4;
    }
  }
  __syncthreads();

  const int wv = t >> 6;          // wave 0..3 -> cols wv*32 .. wv*32+31
  const int l  = t & 63;
  const int lc = l & 15, lk = l >> 4;

  short8 bfrag[2][4];
  #pragma unroll
  for(int tt=0; tt<2; tt++){
    int col = wv*32 + tt*16 + lc;
    #pragma unroll
    for(int s=0; s<4; s++)
      bfrag[tt][s] = *(const short8*)(wT + col*128 + s*32 + lk*8);
  }

  f32x4 acc[8][2];
  #pragma unroll
  for(int m=0;m<8;m++){ acc[m][0] = (f32x4)0.f; acc[m][1] = (f32x4)0.f; }

  #pragma unroll
  for(int m=0; m<8; m++){
    const ushort* ap = lds_a + (m*16 + lc)*136 + lk*8;
    #pragma unroll
    for(int s=0; s<4; s++){
      short8 a = *(const short8*)(ap + s*32);
      acc[m][0] = __builtin_amdgcn_mfma_f32_16x16x32_bf16(a, bfrag[0][s], acc[m][0], 0, 0, 0);
      acc[m][1] = __builtin_amdgcn_mfma_f32_16x16x32_bf16(a, bfrag[1][s], acc[m][1], 0, 0, 0);
    }
  }

  #pragma unroll
  for(int m=0; m<8; m++){
    #pragma unroll
    for(int tt=0; tt<2; tt++){
      int colg = wv*32 + tt*16 + lc;
      #pragma unroll
      for(int r=0; r<4; r++){
        int row = m*16 + lk*4 + r;
        int node = row0 + row;
        if(node < NN)
          g[(size_t)node*128 + colg] = f2b(acc[m][tt][r] * sdinv[row]);
      }
    }
  }
}

// ---------------- lean aggregation over dst-sorted edges (bf16 gather + bf16 out) ----------
// out[n] = bf16( dinv[n]*(sum_{e->n} g[src] + g[n]) + bias )
__global__ __launch_bounds__(256)
void k_agg(const ushort* __restrict__ g, const int* __restrict__ rowstart,
           const int* __restrict__ srcs, const float* __restrict__ dinv,
           const float* __restrict__ bias, ushort* __restrict__ outp)
{
  const int lane = threadIdx.x & 31;          // 4-feat slot
  const int node = blockIdx.x*8 + (threadIdx.x >> 5);
  const int e0 = rowstart[node], e1 = rowstart[node+1];
  float ax=0.f, ay=0.f, az=0.f, aw=0.f;
  float bx=0.f, by=0.f, bz=0.f, bw=0.f;
  const ushort4* gp = (const ushort4*)g;
  int e = e0;
  for(; e+7 < e1; e += 8){                    // 8 outstanding gathers
    int si[8];
    #pragma unroll
    for(int i=0;i<8;i++) si[i] = srcs[e+i];
    ushort4 v[8];
    #pragma unroll
    for(int i=0;i<8;i++) v[i] = gp[(size_t)si[i]*32 + lane];
    #pragma unroll
    for(int i=0;i<8;i++){
      if(i&1){ bx += b2f(v[i].x); by += b2f(v[i].y); bz += b2f(v[i].z); bw += b2f(v[i].w); }
      else   { ax += b2f(v[i].x); ay += b2f(v[i].y); az += b2f(v[i].z); aw += b2f(v[i].w); }
    }
  }
  for(; e+3 < e1; e += 4){
    int si[4];
    #pragma unroll
    for(int i=0;i<4;i++) si[i] = srcs[e+i];
    ushort4 v[4];
    #pragma unroll
    for(int i=0;i<4;i++) v[i] = gp[(size_t)si[i]*32 + lane];
    #pragma unroll
    for(int i=0;i<4;i++){
      if(i&1){ bx += b2f(v[i].x); by += b2f(v[i].y); bz += b2f(v[i].z); bw += b2f(v[i].w); }
      else   { ax += b2f(v[i].x); ay += b2f(v[i].y); az += b2f(v[i].z); aw += b2f(v[i].w); }
    }
  }
  for(; e < e1; e++){
    ushort4 v = gp[(size_t)srcs[e]*32 + lane];
    ax += b2f(v.x); ay += b2f(v.y); az += b2f(v.z); aw += b2f(v.w);
  }
  ushort4 vs = gp[(size_t)node*32 + lane];
  float dv = dinv[node];
  float4 bv = ((const float4*)bias)[lane];
  ushort4 o4;
  o4.x = f2b(dv*(ax+bx+b2f(vs.x))+bv.x);
  o4.y = f2b(dv*(ay+by+b2f(vs.y))+bv.y);
  o4.z = f2b(dv*(az+bz+b2f(vs.z))+bv.z);
  o4.w = f2b(dv*(aw+bw+b2f(vs.w))+bv.w);
  ((ushort4*)outp)[(size_t)node*32 + lane] = o4;
}

// ---------------- per-graph moments from bf16 (one pass: sum x, sum x^2) ----------------
#define STAT_CH 8
__global__ __launch_bounds__(128)
void k_stats(const ushort* __restrict__ x, const int* __restrict__ gstart,
             float* __restrict__ S1, float* __restrict__ S2)
{
  int g = blockIdx.x, ch = blockIdx.y, f = threadIdx.x;
  int s = gstart[g], e = gstart[g+1];
  int len = e - s;
  int i0 = s + (int)((long long)len * ch / STAT_CH);
  int i1 = s + (int)((long long)len * (ch+1) / STAT_CH);
  float a1 = 0.f, a2 = 0.f;
  for(int n=i0; n<i1; n++){
    float v = b2f(x[(size_t)n*128 + f]);
    a1 += v; a2 += v*v;
  }
  if(i1 > i0){
    atomicAdd(&S1[g*128+f], a1);
    atomicAdd(&S2[g*128+f], a2);
  }
}

// ---------------- pooled[g][f] += sum_n relu(norm(x[n][f]))  (norm inline from S1/S2) ------
#define POOL_CH 16
__global__ __launch_bounds__(128)
void k_pool(const ushort* __restrict__ x, const int* __restrict__ gstart,
            const float* __restrict__ gw, const float* __restrict__ gb,
            const float* __restrict__ ga, const float* __restrict__ S1,
            const float* __restrict__ S2, float* __restrict__ pooled)
{
  int g = blockIdx.x, ch = blockIdx.y, f = threadIdx.x;
  int s = gstart[g], e = gstart[g+1];
  int len = e - s;
  int i0 = s + (int)((long long)len * ch / POOL_CH);
  int i1 = s + (int)((long long)len * (ch+1) / POOL_CH);
  float inv = 1.f/(float)(len > 0 ? len : 1);
  float a = ga[f];
  float m = S1[g*128+f]*inv, ex2 = S2[g*128+f]*inv;
  float am = a*m;
  float rs = rsqrtf(ex2 - (2.f*a - a*a)*m*m + EPSV);
  float wv = gw[f], bv = gb[f];
  float a1 = 0.f;
  for(int n=i0; n<i1; n++){
    float v = b2f(x[(size_t)n*128 + f]);
    v = wv*(v-am)*rs + bv;
    a1 += fmaxf(v, 0.f);
  }
  if(i1 > i0) atomicAdd(&pooled[g*128+f], a1);
}

// ---------------- head: logits = pooled/cnt @ lw + lb, log_softmax ----------------
__global__ __launch_bounds__(64)
void k_head(const float* __restrict__ pooled, const int* __restrict__ gstart,
            const float* __restrict__ lw, const float* __restrict__ lb,
            float* __restrict__ out)
{
  int g = blockIdx.x, t = threadIdx.x;
  __shared__ float lg[NC];
  __shared__ float lse_s;
  int len = gstart[g+1] - gstart[g];
  float inv = 1.f/(float)(len > 0 ? len : 1);
  if(t < NC){
    float acc = lb[t];
    for(int f=0; f<128; f++) acc += pooled[g*128+f]*inv*lw[f*NC + t];
    lg[t] = acc;
  }
  __syncthreads();
  if(t == 0){
    float mx = -1e30f;
    for(int c=0;c<NC;c++) mx = fmaxf(mx, lg[c]);
    float sm = 0.f;
    for(int c=0;c<NC;c++) sm += expf(lg[c]-mx);
    lse_s = mx + logf(sm);
  }
  __syncthreads();
  if(t < NC) out[g*NC + t] = lg[t] - lse_s;
}

// ---------------- launch ----------------
extern "C" void kernel_launch(void* const* d_in, const int* in_sizes, int n_in,
                              void* d_out, int out_size, void* d_ws, size_t ws_size,
                              hipStream_t stream)
{
  const float* x    = (const float*)d_in[0];
  const int*   ei   = (const int*)d_in[1];
  const int*   batch= (const int*)d_in[2];
  const float* w1   = (const float*)d_in[3];
  const float* b1   = (const float*)d_in[4];
  const float* w2   = (const float*)d_in[5];
  const float* b2   = (const float*)d_in[6];
  const float* w3   = (const float*)d_in[7];
  const float* b3   = (const float*)d_in[8];
  const float* g1w  = (const float*)d_in[9];
  const float* g1b  = (const float*)d_in[10];
  const float* g1a  = (const float*)d_in[11];
  const float* g2w  = (const float*)d_in[12];
  const float* g2b  = (const float*)d_in[13];
  const float* g2a  = (const float*)d_in[14];
  const float* g3w  = (const float*)d_in[15];
  const float* g3b  = (const float*)d_in[16];
  const float* g3a  = (const float*)d_in[17];
  const float* lw   = (const float*)d_in[18];
  const float* lb   = (const float*)d_in[19];
  float* out = (float*)d_out;

  char* p = (char*)d_ws;
  auto take = [&](size_t nbytes){ char* q = p; p += (nbytes + 255) & ~(size_t)255; return q; };
  ushort* gbuf    = (ushort*)take((size_t)NN*HD*2);
  ushort* bufB    = (ushort*)take((size_t)NN*HD*2);
  ushort* wT      = (ushort*)take((size_t)3*HD*HD*2);
  unsigned* ebuf  = (unsigned*)take((size_t)NE*4);
  int*   srcs     = (int*)  take((size_t)NE*4);
  int*   rowstart = (int*)  take((size_t)(NN+1)*4);
  float* dinv     = (float*)take((size_t)NN*4);
  int*   gbhist   = (int*)  take((size_t)NBKT*4);
  int*   bucket_base   = (int*)take((size_t)(NBKT+1)*4);
  int*   bucket_cursor = (int*)take((size_t)NBKT*4);
  int*   gstart   = (int*)  take((size_t)(NG+1)*4);
  float* Sbase    = (float*)take((size_t)(3*2*NG*HD + NG*HD)*4);  // 3x(S1,S2) + pooled, contiguous
  if((size_t)(p - (char*)d_ws) > ws_size) return;  // workspace too small: fail visibly

  float* SL1 = Sbase;                // layer-1 S1,S2
  float* SL2 = Sbase + 2*NG*HD;
  float* SL3 = Sbase + 4*NG*HD;
  float* pooled = Sbase + 6*NG*HD;

  k_init  <<<409, 256, 0, stream>>>(batch, gstart, w1, w2, w3, wT, gbhist, Sbase);
  k_bhist <<<BIN_BLOCKS, 256, 0, stream>>>(ei, gbhist);
  k_bscan <<<1, 256, 0, stream>>>(gbhist, bucket_base, bucket_cursor, rowstart);
  k_bin   <<<BIN_BLOCKS, 256, 0, stream>>>(ei, bucket_cursor, ebuf);
  k_sort  <<<NBKT, 256, 0, stream>>>(ebuf, bucket_base, srcs, rowstart, dinv);

  const int GB = (NN + 127)/128;     // 782
  const int AB = NN/8;               // 12500

  // ---- layer 1 ----
  k_gemm<0><<<GB, 256, 0, stream>>>(x, wT, gbuf, dinv, batch,
                                    nullptr, nullptr, nullptr, nullptr, nullptr, gstart);
  k_agg<<<AB, 256, 0, stream>>>(gbuf, rowstart, srcs, dinv, b1, bufB);
  k_stats<<<dim3(NG, STAT_CH), 128, 0, stream>>>(bufB, gstart, SL1, SL1 + NG*HD);

  // ---- layer 2 ----
  k_gemm<1><<<GB, 256, 0, stream>>>(bufB, wT + 16384, gbuf, dinv, batch,
                                    g1w, g1b, g1a, SL1, SL1 + NG*HD, gstart);
  k_agg<<<AB, 256, 0, stream>>>(gbuf, rowstart, srcs, dinv, b2, bufB);
  k_stats<<<dim3(NG, STAT_CH), 128, 0, stream>>>(bufB, gstart, SL2, SL2 + NG*HD);

  // ---- layer 3 ----
  k_gemm<1><<<GB, 256, 0, stream>>>(bufB, wT + 32768, gbuf, dinv, batch,
                                    g2w, g2b, g2a, SL2, SL2 + NG*HD, gstart);
  k_agg<<<AB, 256, 0, stream>>>(gbuf, rowstart, srcs, dinv, b3, bufB);
  k_stats<<<dim3(NG, STAT_CH), 128, 0, stream>>>(bufB, gstart, SL3, SL3 + NG*HD);

  // ---- pool + head ----
  k_pool<<<dim3(NG, POOL_CH), 128, 0, stream>>>(bufB, gstart, g3w, g3b, g3a,
                                                SL3, SL3 + NG*HD, pooled);
  k_head<<<NG, 64, 0, stream>>>(pooled, gstart, lw, lb, out);
}